// Round 2
// baseline (93.273 us; speedup 1.0000x reference)
//
#include <hip/hip_runtime.h>
#include <math.h>

#define TPB 256

// integer power by squaring; exponent is wave-uniform (from zetas[])
__device__ __forceinline__ float powi_f(float x, int n) {
    float r = 1.0f, p = x;
    while (n > 0) { if (n & 1) r *= p; p *= p; n >>= 1; }
    return r;
}

__global__ __launch_bounds__(TPB) void behler_ang_kernel(
    const float* __restrict__ positions,  // (B,A,3)
    const float* __restrict__ cell,       // (B,3,3)
    const float* __restrict__ offsets,    // (B,A,N,3)
    const float* __restrict__ etas,       // (E,)
    const int*  __restrict__ zetas,       // (Z,)
    const int*  __restrict__ nbr_j,       // (B,A,T)
    const int*  __restrict__ nbr_k,       // (B,A,T)
    const int*  __restrict__ off_j,       // (B,A,T)
    const int*  __restrict__ off_k,       // (B,A,T)
    const int*  __restrict__ mask,        // (B,A,T)
    float* __restrict__ out,              // (B,A,E*2Z)
    int A, int T, int N)
{
    constexpr int E = 8, Z = 4;
    const int blk = blockIdx.x;
    const int b = blk / A;
    const int a = blk - b * A;
    const int tid = threadIdx.x;

    __shared__ float sPosX[256], sPosY[256], sPosZ[256];   // A <= 256
    __shared__ float sCartX[64], sCartY[64], sCartZ[64];   // N <= 64
    __shared__ float sEta[E];
    __shared__ int   sZeta[Z];
    __shared__ float sRed[TPB / 64][E * Z];

    // stage positions of this batch into LDS (SoA)
    for (int i = tid; i < A; i += TPB) {
        const float* p = positions + ((size_t)b * A + i) * 3;
        sPosX[i] = p[0]; sPosY[i] = p[1]; sPosZ[i] = p[2];
    }
    // cart[n,c] = sum_d offsets[b,a,n,d] * cell[b,d,c]
    const float* cb = cell + (size_t)b * 9;
    for (int n = tid; n < N; n += TPB) {
        const float* o = offsets + (((size_t)b * A + a) * N + n) * 3;
        float ox = o[0], oy = o[1], oz = o[2];
        sCartX[n] = ox * cb[0] + oy * cb[3] + oz * cb[6];
        sCartY[n] = ox * cb[1] + oy * cb[4] + oz * cb[7];
        sCartZ[n] = ox * cb[2] + oy * cb[5] + oz * cb[8];
    }
    if (tid < E) sEta[tid] = etas[tid];
    if (tid < Z) sZeta[tid] = zetas[tid];
    __syncthreads();

    const float rix = sPosX[a], riy = sPosY[a], riz = sPosZ[a];

    float acc[E][Z];
    #pragma unroll
    for (int e = 0; e < E; ++e)
        #pragma unroll
        for (int z = 0; z < Z; ++z) acc[e][z] = 0.0f;

    const size_t tb = ((size_t)b * A + a) * T;
    const float PI_OVER_RC = 0.6283185307179586f;  // pi / 5.0

    for (int t = tid; t < T; t += TPB) {
        // issue all loads unconditionally (cacheline is fetched regardless
        // of mask; hoisting lets the compiler cluster the global_loads)
        int m  = mask[tb + t];
        int j  = nbr_j[tb + t], k  = nbr_k[tb + t];
        int fj = off_j[tb + t], fk = off_k[tb + t];
        if (m == 0) continue;   // contributes exactly 0

        float pjx = sPosX[j] + sCartX[fj];
        float pjy = sPosY[j] + sCartY[fj];
        float pjz = sPosZ[j] + sCartZ[fj];
        float pkx = sPosX[k] + sCartX[fk];
        float pky = sPosY[k] + sCartY[fk];
        float pkz = sPosZ[k] + sCartZ[fk];

        float djx = pjx - rix, djy = pjy - riy, djz = pjz - riz;
        float dkx = pkx - rix, dky = pky - riy, dkz = pkz - riz;
        float dex = pkx - pjx, dey = pky - pjy, dez = pkz - pjz;

        float d2ij = fmaxf(djx * djx + djy * djy + djz * djz, 1e-12f);
        float d2ik = fmaxf(dkx * dkx + dky * dky + dkz * dkz, 1e-12f);
        float d2jk = fmaxf(dex * dex + dey * dey + dez * dez, 1e-12f);

        // any r >= RC => cutoff factor is 0 => zero contribution
        if (d2ij >= 25.0f || d2ik >= 25.0f || d2jk >= 25.0f) continue;

        float rij = sqrtf(d2ij), rik = sqrtf(d2ik), rjk = sqrtf(d2jk);
        float r2 = d2ij + d2ik + d2jk;

        float cut = 0.125f * (__cosf(rij * PI_OVER_RC) + 1.0f)
                           * (__cosf(rik * PI_OVER_RC) + 1.0f)
                           * (__cosf(rjk * PI_OVER_RC) + 1.0f);

        float cost = r2 / (2.0f * rij * rik);
        float x = 1.0f - cost;

        float bz[Z];
        #pragma unroll
        for (int z = 0; z < Z; ++z) bz[z] = powi_f(x, sZeta[z]);

        #pragma unroll
        for (int e = 0; e < E; ++e) {
            float rad = __expf(-sEta[e] * r2) * cut;
            #pragma unroll
            for (int z = 0; z < Z; ++z)
                acc[e][z] = fmaf(rad, bz[z], acc[e][z]);
        }
    }

    // ---- reduction: wave butterfly, then cross-wave via LDS ----
    const int lane = tid & 63, wave = tid >> 6;
    #pragma unroll
    for (int e = 0; e < E; ++e) {
        #pragma unroll
        for (int z = 0; z < Z; ++z) {
            float v = acc[e][z];
            v += __shfl_down(v, 32);
            v += __shfl_down(v, 16);
            v += __shfl_down(v, 8);
            v += __shfl_down(v, 4);
            v += __shfl_down(v, 2);
            v += __shfl_down(v, 1);
            if (lane == 0) sRed[wave][e * Z + z] = v;
        }
    }
    __syncthreads();

    if (tid < E * Z) {
        float v = 0.0f;
        #pragma unroll
        for (int w = 0; w < TPB / 64; ++w) v += sRed[w][tid];
        int e = tid >> 2;        // Z == 4
        int z = tid & 3;
        int zt = sZeta[z];
        float pm = ldexpf(1.0f, 1 - zt);  // 2^(1-zeta)
        float pp = ldexpf(1.0f, 1 + zt);  // 2^(1+zeta)
        size_t ob = (((size_t)b * A + a) * E + e) * (2 * Z);
        out[ob + z]     = pm * v;
        out[ob + Z + z] = pp * v;
    }
}

extern "C" void kernel_launch(void* const* d_in, const int* in_sizes, int n_in,
                              void* d_out, int out_size, void* d_ws, size_t ws_size,
                              hipStream_t stream) {
    const float* positions = (const float*)d_in[0];
    const float* cell      = (const float*)d_in[1];
    const float* offsets   = (const float*)d_in[2];
    const float* etas      = (const float*)d_in[3];
    const int*   zetas     = (const int*)d_in[4];
    const int*   nj        = (const int*)d_in[5];
    const int*   nk        = (const int*)d_in[6];
    const int*   oj        = (const int*)d_in[7];
    const int*   ok        = (const int*)d_in[8];
    const int*   msk       = (const int*)d_in[9];
    float* out = (float*)d_out;

    int B = in_sizes[1] / 9;
    int A = in_sizes[0] / (3 * B);
    int N = in_sizes[2] / (B * A * 3);
    int T = in_sizes[5] / (B * A);

    behler_ang_kernel<<<B * A, TPB, 0, stream>>>(
        positions, cell, offsets, etas, zetas, nj, nk, oj, ok, msk, out, A, T, N);
}